// Round 6
// baseline (894.197 us; speedup 1.0000x reference)
//
#include <hip/hip_runtime.h>
#include <hip/hip_bf16.h>
#include <stdint.h>

#define N_ROWS 16384
#define E_DIM 512
#define C_DIM 128
#define K_CODES 2048
#define M_BOOKS 4
#define H1_DIM 128
#define H2_DIM 256
#define EPS_V 1e-5f

// ---- fused GEMM, 256x128 tile, 16x8 per thread ----
// Per kk: 6 ds_read_b128 (96B) per 128 FMA = 0.375 B/FLOP (was 0.5 -> LDS-bound).
// Thread rows: (i>>2)*64 + ty*4 + (i&3)  (4 groups at 64-stride: a-reads broadcast,
// staging stores 2-way). Cols: tx*4+j / 64+tx*4+j (2-way b-reads). Conflict-free.
// fma chain over k ascending == bitwise-identical to prior rounds.
template<bool BNRELU>
__global__ __launch_bounds__(256, 2) void gemm256(
    const float* __restrict__ A, const float* __restrict__ B,
    const float* __restrict__ bias, const float* __restrict__ bn_g,
    const float* __restrict__ bn_b, const float* __restrict__ bn_m,
    const float* __restrict__ bn_v, float* __restrict__ C,
    int Kd, int Hc, size_t sA, size_t sB, size_t sP, size_t sC)
{
    __shared__ float As[32][256];   // k-major, 32KB
    __shared__ float Bs[32][128];   // k-major, 16KB
    const int z = blockIdx.z;
    A += (size_t)z * sA;
    B += (size_t)z * sB;
    bias += (size_t)z * sP;
    if (BNRELU) {
        bn_g += (size_t)z * sP; bn_b += (size_t)z * sP;
        bn_m += (size_t)z * sP; bn_v += (size_t)z * sP;
    }

    const int t = threadIdx.x;
    const int tx = t & 15, ty = t >> 4;
    const int row0 = blockIdx.y * 256;
    const int col0 = blockIdx.x * 128;
    const int bc = (t & 31) * 4;        // B staging: coalesced, 2-way stores
    const int bk0 = t >> 5;             // {0..7}; +8 per l

    float acc[16][8] = {};
    for (int k0 = 0; k0 < Kd; k0 += 32) {
        // A: thread t owns global row row0+t; 8 x b128 cover k0..k0+31.
        // ds_write addr = (k*256 + t)*4 -> bank t%32 -> 2-way across wave. Free.
        const float* arow = A + (size_t)(row0 + t) * Kd + k0;
        #pragma unroll
        for (int l = 0; l < 8; ++l) {
            float4 av = *(const float4*)(arow + l * 4);
            As[l*4+0][t] = av.x; As[l*4+1][t] = av.y;
            As[l*4+2][t] = av.z; As[l*4+3][t] = av.w;
        }
        #pragma unroll
        for (int l = 0; l < 4; ++l) {
            const int kb = bk0 + l * 8;
            *(float4*)&Bs[kb][bc] =
                *(const float4*)(B + (size_t)(k0 + kb) * Hc + (col0 + bc));
        }
        __syncthreads();
        #pragma unroll
        for (int kk = 0; kk < 32; ++kk) {
            float a[16], b[8];
            *(float4*)&a[0]  = *(const float4*)&As[kk][ty*4];         // broadcast
            *(float4*)&a[4]  = *(const float4*)&As[kk][64 + ty*4];
            *(float4*)&a[8]  = *(const float4*)&As[kk][128 + ty*4];
            *(float4*)&a[12] = *(const float4*)&As[kk][192 + ty*4];
            *(float4*)&b[0]  = *(const float4*)&Bs[kk][tx*4];         // 2-way
            *(float4*)&b[4]  = *(const float4*)&Bs[kk][64 + tx*4];
            #pragma unroll
            for (int i = 0; i < 16; ++i)
                #pragma unroll
                for (int j = 0; j < 8; ++j)
                    acc[i][j] = fmaf(a[i], b[j], acc[i][j]);
        }
        __syncthreads();
    }

    float bi[8], sc[8], mu[8], be[8];
    #pragma unroll
    for (int j = 0; j < 8; ++j) {
        const int col = col0 + ((j < 4) ? (tx*4 + j) : (64 + tx*4 + j - 4));
        bi[j] = bias[col];
        if (BNRELU) {
            sc[j] = bn_g[col] / sqrtf(bn_v[col] + EPS_V);
            mu[j] = bn_m[col]; be[j] = bn_b[col];
        }
    }
    #pragma unroll
    for (int i = 0; i < 16; ++i) {
        const int row = row0 + (i >> 2) * 64 + ty*4 + (i & 3);
        float v[8];
        #pragma unroll
        for (int j = 0; j < 8; ++j) {
            v[j] = acc[i][j] + bi[j];
            if (BNRELU) {
                float p = (v[j] - mu[j]) * sc[j];
                asm volatile("" : "+v"(p));   // separate rounding like numpy
                v[j] = fmaxf(p + be[j], 0.0f);
            }
        }
        float* cp = C + (size_t)z * sC + (size_t)row * Hc + col0;
        *(float4*)(cp + tx*4)      = *(const float4*)&v[0];
        *(float4*)(cp + 64 + tx*4) = *(const float4*)&v[4];
    }
}

// ---- row-wise sum of squares, emulating numpy's 8-accumulator pairwise sum ----
__global__ __launch_bounds__(256) void rowsq_np(const float* __restrict__ X,
                                                float* __restrict__ out, int rows)
{
    const int r = blockIdx.x * blockDim.x + threadIdx.x;
    if (r >= rows) return;
    const float* p = X + (size_t)r * C_DIM;
    float rr[8];
    #pragma unroll
    for (int j = 0; j < 8; ++j) {
        float v = p[j]; float s2 = v * v;
        asm volatile("" : "+v"(s2));
        rr[j] = s2;
    }
    for (int i = 8; i < C_DIM; i += 8) {
        #pragma unroll
        for (int j = 0; j < 8; ++j) {
            float v = p[i + j]; float s2 = v * v;
            asm volatile("" : "+v"(s2));    // keep mul+add separate (no fma), like np
            rr[j] = rr[j] + s2;
        }
    }
    out[r] = ((rr[0]+rr[1]) + (rr[2]+rr[3])) + ((rr[4]+rr[5]) + (rr[6]+rr[7]));
}

// ---- VQ: 256x128 cross GEMM (ze @ cb^T) fused with argmin ----
// Per-thread best -> u64 (distbits<<32|code); LDS u64-min across 16 threads
// (lexicographic == first-index argmin); global merge via atomicMin.
__global__ __launch_bounds__(256, 2) void vq_argmin(
    const float* __restrict__ ze, const float* __restrict__ cb,
    const float* __restrict__ ze_sq, const float* __restrict__ cb_sq,
    unsigned long long* __restrict__ keys)
{
    __shared__ __align__(16) char smem_raw[49152];
    float* As = (float*)smem_raw;                       // [32][256]
    float* Bs = As + 32*256;                            // [32][128]
    unsigned long long* kb = (unsigned long long*)smem_raw;  // [256][17] overlay

    const int m = blockIdx.z;
    const float* Zm  = ze + (size_t)m * N_ROWS * C_DIM;
    const float* Bm  = cb + (size_t)m * K_CODES * C_DIM;
    const float* zsm = ze_sq + (size_t)m * N_ROWS;
    const float* csm = cb_sq + (size_t)m * K_CODES;

    const int t = threadIdx.x;
    const int tx = t & 15, ty = t >> 4;
    const int row0 = blockIdx.y * 256;
    const int col0 = blockIdx.x * 128;
    const int bc = (t & 31) * 4;

    float acc[16][8] = {};
    for (int k0 = 0; k0 < C_DIM; k0 += 32) {
        const float* zrow = Zm + (size_t)(row0 + t) * C_DIM + k0;
        #pragma unroll
        for (int l = 0; l < 8; ++l) {
            float4 av = *(const float4*)(zrow + l * 4);
            As[(l*4+0)*256 + t] = av.x; As[(l*4+1)*256 + t] = av.y;
            As[(l*4+2)*256 + t] = av.z; As[(l*4+3)*256 + t] = av.w;
        }
        // B (codes): rows are codebook vectors; stage transposed like A.
        const int brow = t & 127;       // code within tile
        const int bko = (t >> 7) * 16;  // {0,16}
        const float* crow = Bm + (size_t)(col0 + brow) * C_DIM + k0 + bko;
        #pragma unroll
        for (int l = 0; l < 4; ++l) {
            float4 bv = *(const float4*)(crow + l * 4);
            Bs[(bko+l*4+0)*128 + brow] = bv.x; Bs[(bko+l*4+1)*128 + brow] = bv.y;
            Bs[(bko+l*4+2)*128 + brow] = bv.z; Bs[(bko+l*4+3)*128 + brow] = bv.w;
        }
        __syncthreads();
        #pragma unroll
        for (int kk = 0; kk < 32; ++kk) {
            float a[16], b[8];
            *(float4*)&a[0]  = *(const float4*)&As[kk*256 + ty*4];
            *(float4*)&a[4]  = *(const float4*)&As[kk*256 + 64 + ty*4];
            *(float4*)&a[8]  = *(const float4*)&As[kk*256 + 128 + ty*4];
            *(float4*)&a[12] = *(const float4*)&As[kk*256 + 192 + ty*4];
            *(float4*)&b[0]  = *(const float4*)&Bs[kk*128 + tx*4];
            *(float4*)&b[4]  = *(const float4*)&Bs[kk*128 + 64 + tx*4];
            #pragma unroll
            for (int i = 0; i < 16; ++i)
                #pragma unroll
                for (int j = 0; j < 8; ++j)
                    acc[i][j] = fmaf(a[i], b[j], acc[i][j]);
        }
        __syncthreads();
    }

    // per-thread best over its 8 codes for each of its 16 rows -> u64 keys
    unsigned long long mykey[16];
    #pragma unroll
    for (int i = 0; i < 16; ++i) {
        const int rloc = (i >> 2) * 64 + ty*4 + (i & 3);
        const float zs = zsm[row0 + rloc];
        unsigned long long bk = 0xFFFFFFFFFFFFFFFFull;
        #pragma unroll
        for (int j = 0; j < 8; ++j) {
            const int code = col0 + ((j < 4) ? (tx*4 + j) : (64 + tx*4 + j - 4));
            const float d = (zs + csm[code]) - 2.0f * acc[i][j];  // reference order
            unsigned int ub = __float_as_uint(d);
            ub = (ub & 0x80000000u) ? ~ub : (ub | 0x80000000u);   // monotone map
            const unsigned long long key =
                ((unsigned long long)ub << 32) | (unsigned int)code;
            bk = (key < bk) ? key : bk;     // lexicographic (dist, code) min
        }
        mykey[i] = bk;
    }
    __syncthreads();   // done with As/Bs; reuse LDS for keys
    #pragma unroll
    for (int i = 0; i < 16; ++i) {
        const int rloc = (i >> 2) * 64 + ty*4 + (i & 3);
        kb[rloc*17 + tx] = mykey[i];
    }
    __syncthreads();
    {
        unsigned long long bk = kb[t*17];
        #pragma unroll
        for (int k2 = 1; k2 < 16; ++k2) {
            const unsigned long long k = kb[t*17 + k2];
            bk = (k < bk) ? k : bk;
        }
        atomicMin(&keys[(size_t)m * N_ROWS + row0 + t], bk);
    }
}

// ---- gather chosen codes: ce (fp32 out) + zq = sum_m ce ----
__global__ __launch_bounds__(256) void gather_ce_zq(
    const unsigned long long* __restrict__ keys, const float* __restrict__ cb,
    float* __restrict__ ce_out, float* __restrict__ zq)
{
    const int gid = blockIdx.x * 256 + threadIdx.x;
    const int n = gid >> 7, c = gid & 127;
    float s = 0.0f;
    #pragma unroll
    for (int m = 0; m < M_BOOKS; ++m) {
        const int idx = (int)(keys[(size_t)m * N_ROWS + n] & 0xFFFFFFFFull);
        const float v = cb[((size_t)m * K_CODES + idx) * C_DIM + c];
        ce_out[((size_t)m * N_ROWS + n) * (size_t)C_DIM + c] = v;
        s += v;   // sequential over m, matches np.sum(axis=0) for M=4
    }
    zq[gid] = s;
}

extern "C" void kernel_launch(void* const* d_in, const int* in_sizes, int n_in,
                              void* d_out, int out_size, void* d_ws, size_t ws_size,
                              hipStream_t stream)
{
    const float* x   = (const float*)d_in[0];
    const float* eW1 = (const float*)d_in[1];
    const float* eb1 = (const float*)d_in[2];
    const float* g1  = (const float*)d_in[3];
    const float* b1  = (const float*)d_in[4];
    const float* m1  = (const float*)d_in[5];
    const float* v1  = (const float*)d_in[6];
    const float* eW2 = (const float*)d_in[7];
    const float* eb2 = (const float*)d_in[8];
    const float* g2  = (const float*)d_in[9];
    const float* b2  = (const float*)d_in[10];
    const float* m2  = (const float*)d_in[11];
    const float* v2  = (const float*)d_in[12];
    const float* eW3 = (const float*)d_in[13];
    const float* eb3 = (const float*)d_in[14];
    const float* cb  = (const float*)d_in[15];
    const float* dW1 = (const float*)d_in[16];
    const float* db1 = (const float*)d_in[17];
    const float* dg1 = (const float*)d_in[18];
    const float* dbb1= (const float*)d_in[19];
    const float* dm1 = (const float*)d_in[20];
    const float* dv1 = (const float*)d_in[21];
    const float* dW2 = (const float*)d_in[22];
    const float* db2 = (const float*)d_in[23];
    const float* dg2 = (const float*)d_in[24];
    const float* dbb2= (const float*)d_in[25];
    const float* dm2 = (const float*)d_in[26];
    const float* dv2 = (const float*)d_in[27];
    const float* dW3 = (const float*)d_in[28];
    const float* db3 = (const float*)d_in[29];

    // Outputs are FLOAT32: x_hat[N,E], ze[M,N,C], ce[M,N,C]
    float* out_xhat = (float*)d_out;
    float* out_ze   = out_xhat + (size_t)N_ROWS * E_DIM;
    float* out_ce   = out_ze + (size_t)M_BOOKS * N_ROWS * C_DIM;

    float* ws = (float*)d_ws;
    const size_t h1N1 = (size_t)N_ROWS * H1_DIM;           // 2097152
    const size_t h2N1 = (size_t)N_ROWS * H2_DIM;           // 4194304
    const size_t smallN = (size_t)M_BOOKS*N_ROWS + (size_t)M_BOOKS*K_CODES
                        + 2 + 2*(size_t)M_BOOKS*N_ROWS;
    const size_t fullFloats = (size_t)M_BOOKS*(h1N1 + h2N1) + smallN;
    const bool fullM = ws_size >= fullFloats * sizeof(float) + 256;

    size_t off = 0;
    float* h1 = ws; off += (fullM ? M_BOOKS : 1) * h1N1;
    float* h2 = ws + off; off += (fullM ? M_BOOKS : 1) * h2N1;
    float* zesq = ws + off; off += (size_t)M_BOOKS * N_ROWS;
    float* cbsq = ws + off; off += (size_t)M_BOOKS * K_CODES;
    off = (off + 1) & ~(size_t)1;
    unsigned long long* keys = (unsigned long long*)(ws + off);
    float* zq = h1;   // reuse after encoders finish
    float* d1 = h2;
    float* d2 = h1;   // zq dead once decoder L1 done

    hipMemsetAsync((void*)keys, 0xFF, (size_t)M_BOOKS * N_ROWS * 8, stream);

    dim3 blk(256, 1, 1);
    const int nz = fullM ? M_BOOKS : 1;
    const int nloop = fullM ? 1 : M_BOOKS;
    for (int p = 0; p < nloop; ++p) {
        const size_t mb = fullM ? 0 : (size_t)p;
        // encoder L1: x[N,E] @ W1[E,H1] + BN + ReLU
        gemm256<true><<<dim3(H1_DIM/128, N_ROWS/256, nz), blk, 0, stream>>>(
            x, eW1 + mb * (size_t)E_DIM * H1_DIM,
            eb1 + mb*H1_DIM, g1 + mb*H1_DIM, b1 + mb*H1_DIM, m1 + mb*H1_DIM, v1 + mb*H1_DIM,
            h1, E_DIM, H1_DIM,
            0, (size_t)E_DIM * H1_DIM, H1_DIM, h1N1);
        // encoder L2: h1 @ W2[H1,H2] + BN + ReLU
        gemm256<true><<<dim3(H2_DIM/128, N_ROWS/256, nz), blk, 0, stream>>>(
            h1, eW2 + mb * (size_t)H1_DIM * H2_DIM,
            eb2 + mb*H2_DIM, g2 + mb*H2_DIM, b2 + mb*H2_DIM, m2 + mb*H2_DIM, v2 + mb*H2_DIM,
            h2, H1_DIM, H2_DIM,
            h1N1, (size_t)H1_DIM * H2_DIM, H2_DIM, h2N1);
        // encoder L3: h2 @ W3[H2,C] + bias -> ze straight into d_out (fp32)
        gemm256<false><<<dim3(C_DIM/128, N_ROWS/256, nz), blk, 0, stream>>>(
            h2, eW3 + mb * (size_t)H2_DIM * C_DIM,
            eb3 + mb*C_DIM, nullptr, nullptr, nullptr, nullptr,
            out_ze + mb * (size_t)N_ROWS * C_DIM, H2_DIM, C_DIM,
            h2N1, (size_t)H2_DIM * C_DIM, C_DIM, (size_t)N_ROWS * C_DIM);
    }

    rowsq_np<<<dim3((M_BOOKS * N_ROWS) / 256), blk, 0, stream>>>(out_ze, zesq, M_BOOKS * N_ROWS);
    rowsq_np<<<dim3((M_BOOKS * K_CODES) / 256), blk, 0, stream>>>(cb, cbsq, M_BOOKS * K_CODES);
    vq_argmin<<<dim3(K_CODES/128, N_ROWS/256, M_BOOKS), blk, 0, stream>>>(
        out_ze, cb, zesq, cbsq, keys);
    gather_ce_zq<<<dim3((N_ROWS * C_DIM) / 256), blk, 0, stream>>>(keys, cb, out_ce, zq);

    // decoder
    gemm256<true><<<dim3(H2_DIM/128, N_ROWS/256, 1), blk, 0, stream>>>(
        zq, dW1, db1, dg1, dbb1, dm1, dv1, d1, C_DIM, H2_DIM, 0, 0, 0, 0);
    gemm256<true><<<dim3(H1_DIM/128, N_ROWS/256, 1), blk, 0, stream>>>(
        d1, dW2, db2, dg2, dbb2, dm2, dv2, d2, H2_DIM, H1_DIM, 0, 0, 0, 0);
    gemm256<false><<<dim3(E_DIM/128, N_ROWS/256, 1), blk, 0, stream>>>(
        d2, dW3, db3, nullptr, nullptr, nullptr, nullptr,
        out_xhat, H1_DIM, E_DIM, 0, 0, 0, 0);
}